// Round 3
// baseline (549.416 us; speedup 1.0000x reference)
//
#include <hip/hip_runtime.h>
#include <math.h>

#define NB  64
#define TT  1024
#define H2  512      // 2*H
#define SS  128      // style dim
#define OO  80
#define FIN_A 896    // 3H+S (ga_ih inner dim)
#define FIN_1 1152   // 4H+S (wsc / g1_ih inner dim)
#define CH  32       // t-chunks for apply (32 t per block, 8 per wave)

__device__ __forceinline__ float fast_rcp(float x) { return __builtin_amdgcn_rcpf(x); }
__device__ __forceinline__ float fast_sigmoid(float x) { return fast_rcp(1.0f + __expf(-x)); }
// tanh = 1 - 2/(e^{2x}+1); handles +-inf correctly via rcp(inf)=0
__device__ __forceinline__ float fast_tanh(float x) {
    float e = __expf(2.0f * x);
    return 1.0f - 2.0f * fast_rcp(e + 1.0f);
}
__device__ __forceinline__ float wred(float p) {
    #pragma unroll
    for (int o = 32; o > 0; o >>= 1) p += __shfl_xor(p, o, 64);
    return p;
}
__device__ __forceinline__ int rfl(int x) { return __builtin_amdgcn_readfirstlane(x); }

// ---- Stage 1: t1T[i][n] = relu(input_dec @ pw1.T + pb1)^T ; blocks 128..159: svT copies
__global__ void k_l1(const float* __restrict__ xdec, const float* __restrict__ pw1,
                     const float* __restrict__ pb1, const float* __restrict__ sv,
                     float* __restrict__ t1T, float* __restrict__ xaT,
                     float* __restrict__ out_decT) {
    int wv = threadIdx.x >> 6, lane = threadIdx.x & 63;
    if (blockIdx.x < 128) {
        int i = rfl(blockIdx.x * 4 + wv);            // 0..511
        const float* w = pw1 + i * OO;
        const float* x = xdec + lane * OO;
        float acc = 0.0f;
        #pragma unroll 8
        for (int k = 0; k < OO; ++k) acc += w[k] * x[k];
        t1T[i * 64 + lane] = fmaxf(acc + pb1[i], 0.0f);
    } else {
        int s = (blockIdx.x - 128) * 4 + wv;         // 0..127
        float v = sv[lane * SS + s];
        xaT[(256 + s) * 64 + lane] = v;              // sv rows of attention-GRU input
        out_decT[(1024 + s) * 64 + lane] = v;        // sv rows of out_dec
    }
}

// ---- Stage 2: xaT rows 0..255 = preT = relu(t1 @ pw2.T + pb2)^T
__global__ void k_l2(const float* __restrict__ t1T, const float* __restrict__ pw2,
                     const float* __restrict__ pb2, float* __restrict__ xaT) {
    int i = rfl(blockIdx.x * 4 + (threadIdx.x >> 6));   // 0..255
    int lane = threadIdx.x & 63;
    const float* w = pw2 + (size_t)i * H2;
    float acc = 0.0f;
    #pragma unroll 16
    for (int k = 0; k < H2; ++k) acc += w[k] * t1T[k * 64 + lane];
    xaT[i * 64 + lane] = fmaxf(acc + pb2[i], 0.0f);
}

// ---- Stage 3: attention GRU (h=0, ctx=0): out_decT rows 512..1023 = out_att^T
__global__ void k_gruA(const float* __restrict__ xaT, const float* __restrict__ ga_ih,
                       const float* __restrict__ ga_bih, const float* __restrict__ ga_bhh,
                       float* __restrict__ out_decT) {
    int j = rfl(blockIdx.x * 4 + (threadIdx.x >> 6));   // 0..511
    int lane = threadIdx.x & 63;
    const float* wr = ga_ih + (size_t)j * FIN_A;
    const float* wz = ga_ih + (size_t)(H2 + j) * FIN_A;
    const float* wn = ga_ih + (size_t)(2 * H2 + j) * FIN_A;
    float pr = 0.0f, pz = 0.0f, pn = 0.0f;
    #pragma unroll 8
    for (int k = 0; k < 256; ++k) {                 // pre part (cols 0..255)
        float xv = xaT[k * 64 + lane];
        pr += wr[k] * xv; pz += wz[k] * xv; pn += wn[k] * xv;
    }
    #pragma unroll 8
    for (int k = 0; k < 128; ++k) {                 // sv part (cols 768..895)
        float xv = xaT[(256 + k) * 64 + lane];
        pr += wr[768 + k] * xv; pz += wz[768 + k] * xv; pn += wn[768 + k] * xv;
    }
    float r = fast_sigmoid(pr + ga_bih[j] + ga_bhh[j]);
    float z = fast_sigmoid(pz + ga_bih[H2 + j] + ga_bhh[H2 + j]);
    float nn = fast_tanh(pn + ga_bih[2 * H2 + j] + r * ga_bhh[2 * H2 + j]);
    out_decT[(size_t)(H2 + j) * 64 + lane] = (1.0f - z) * nn;
}

// ---- Stage 4: attW_dec[n][i] = out_att @ wdec.T + bdec  (scatter store, [n][512] layout)
__global__ void k_attw(const float* __restrict__ out_decT, const float* __restrict__ wdec,
                       const float* __restrict__ bdec, float* __restrict__ attW_dec) {
    int i = rfl(blockIdx.x * 4 + (threadIdx.x >> 6));   // 0..511
    int lane = threadIdx.x & 63;
    const float* w = wdec + (size_t)i * H2;
    float acc = 0.0f;
    #pragma unroll 16
    for (int k = 0; k < H2; ++k) acc += w[k] * out_decT[(size_t)(H2 + k) * 64 + lane];
    attW_dec[lane * H2 + i] = acc + bdec[i];
}

// ---- Stage 5: scores. wave per (n,t) row: ew = mask * exp(tanh-dot + b), unnormalized
__global__ void k_score(const float* __restrict__ attw_enc, const float* __restrict__ attW_dec,
                        const float* __restrict__ wattn, const float* __restrict__ battn,
                        const int* __restrict__ lengths, float* __restrict__ ew) {
    int wv = threadIdx.x >> 6, lane = threadIdx.x & 63;
    int row = blockIdx.x * 4 + wv;                  // n*1024 + t
    int n = row >> 10, t = row & 1023;
    const float4* e4 = (const float4*)(attw_enc + (size_t)row * H2);
    const float4* d4 = (const float4*)(attW_dec + n * H2);
    const float4* w4 = (const float4*)wattn;
    float p = 0.0f;
    #pragma unroll
    for (int m = 0; m < 2; ++m) {
        int idx = lane + m * 64;
        float4 e = e4[idx], d = d4[idx], w = w4[idx];
        p += fast_tanh(e.x + d.x) * w.x + fast_tanh(e.y + d.y) * w.y +
             fast_tanh(e.z + d.z) * w.z + fast_tanh(e.w + d.w) * w.w;
    }
    p = wred(p);
    if (lane == 0) ew[row] = (t < lengths[n]) ? __expf(p + battn[0]) : 0.0f;
}

// ---- Stage 6: weighted sum partials. block (c, n); pure streaming FMA
__global__ void k_apply(const float* __restrict__ enc, const float* __restrict__ ew,
                        float* __restrict__ num_part /*[CH][NB][512]*/,
                        float* __restrict__ den_part /*[CH][NB]*/) {
    int n = blockIdx.y, c = blockIdx.x;
    int wv = threadIdx.x >> 6, lane = threadIdx.x & 63;
    int t0 = c * (TT / CH) + wv * (TT / CH / 4);
    int d0 = lane * 8;
    const float* base = enc + ((size_t)n * TT + t0) * H2 + d0;
    const float* ewp = ew + n * TT + t0;
    float4 a0 = {0, 0, 0, 0}, a1 = {0, 0, 0, 0};
    float dp = 0.0f;
    #pragma unroll
    for (int t = 0; t < TT / CH / 4; ++t) {
        float wt = ewp[t];
        const float4* v4 = (const float4*)(base + (size_t)t * H2);
        float4 v0 = v4[0], v1 = v4[1];
        a0.x += wt * v0.x; a0.y += wt * v0.y; a0.z += wt * v0.z; a0.w += wt * v0.w;
        a1.x += wt * v1.x; a1.y += wt * v1.y; a1.z += wt * v1.z; a1.w += wt * v1.w;
        dp += wt;
    }
    __shared__ float s[4 * 512];
    __shared__ float sd[4];
    float4* srow = (float4*)(s + wv * 512 + d0);
    srow[0] = a0; srow[1] = a1;
    if (lane == 0) sd[wv] = dp;
    __syncthreads();
    int d = threadIdx.x;
    float r0 = s[d] + s[512 + d] + s[1024 + d] + s[1536 + d];
    float r1 = s[256 + d] + s[768 + d] + s[1280 + d] + s[1792 + d];
    float* np = num_part + ((size_t)c * NB + n) * H2;
    np[d] = r0;
    np[256 + d] = r1;
    if (threadIdx.x == 0) den_part[c * NB + n] = sd[0] + sd[1] + sd[2] + sd[3];
}

// ---- Stage 7: reduce partials; write attn_applied (output 1) + out_decT rows 0..511
__global__ void k_reduce(const float* __restrict__ num_part, const float* __restrict__ den_part,
                         float* __restrict__ out, float* __restrict__ out_decT) {
    int d = blockIdx.x * 4 + (threadIdx.x >> 6);    // 0..511
    int lane = threadIdx.x & 63;                    // n
    float s = 0.0f;
    #pragma unroll
    for (int c = 0; c < CH; ++c) s += num_part[((size_t)c * NB + lane) * H2 + d];
    float den = 0.0f;
    #pragma unroll
    for (int c = 0; c < CH; ++c) den += den_part[c * NB + lane];
    float a = s / fmaxf(den, 1e-12f);
    out_decT[(size_t)d * 64 + lane] = a;
    out[NB * 160 + lane * H2 + d] = a;              // output 1: attn_applied (n-major)
}

// ---- Stage 8: res1T = (out_dec @ wsc.T + bsc + GRU1(out_dec,0))^T ; G=4 rows per wave
__global__ void k_sc_h1(const float* __restrict__ out_decT, const float* __restrict__ wsc,
                        const float* __restrict__ bsc, const float* __restrict__ g1_ih,
                        const float* __restrict__ g1_bih, const float* __restrict__ g1_bhh,
                        float* __restrict__ res1T) {
    int j = rfl(blockIdx.x * 4 + (threadIdx.x >> 6));   // 0..511
    int lane = threadIdx.x & 63;
    const float* ws_ = wsc + (size_t)j * FIN_1;
    const float* wr = g1_ih + (size_t)j * FIN_1;
    const float* wz = g1_ih + (size_t)(H2 + j) * FIN_1;
    const float* wn = g1_ih + (size_t)(2 * H2 + j) * FIN_1;
    float ps = 0.0f, pr = 0.0f, pz = 0.0f, pn = 0.0f;
    #pragma unroll 8
    for (int k = 0; k < FIN_1; ++k) {
        float xv = out_decT[(size_t)k * 64 + lane];
        ps += ws_[k] * xv; pr += wr[k] * xv; pz += wz[k] * xv; pn += wn[k] * xv;
    }
    float r = fast_sigmoid(pr + g1_bih[j] + g1_bhh[j]);
    float z = fast_sigmoid(pz + g1_bih[H2 + j] + g1_bhh[H2 + j]);
    float nn = fast_tanh(pn + g1_bih[2 * H2 + j] + r * g1_bhh[2 * H2 + j]);
    res1T[j * 64 + lane] = ps + bsc[j] + (1.0f - z) * nn;
}

// ---- Stage 9: res2T = res1T + GRU2(res1,0)^T
__global__ void k_h2(const float* __restrict__ res1T, const float* __restrict__ g2_ih,
                     const float* __restrict__ g2_bih, const float* __restrict__ g2_bhh,
                     float* __restrict__ res2T) {
    int j = rfl(blockIdx.x * 4 + (threadIdx.x >> 6));   // 0..511
    int lane = threadIdx.x & 63;
    const float* wr = g2_ih + (size_t)j * H2;
    const float* wz = g2_ih + (size_t)(H2 + j) * H2;
    const float* wn = g2_ih + (size_t)(2 * H2 + j) * H2;
    float pr = 0.0f, pz = 0.0f, pn = 0.0f;
    #pragma unroll 8
    for (int k = 0; k < H2; ++k) {
        float xv = res1T[k * 64 + lane];
        pr += wr[k] * xv; pz += wz[k] * xv; pn += wn[k] * xv;
    }
    float r = fast_sigmoid(pr + g2_bih[j] + g2_bhh[j]);
    float z = fast_sigmoid(pz + g2_bih[H2 + j] + g2_bhh[H2 + j]);
    float nn = fast_tanh(pn + g2_bih[2 * H2 + j] + r * g2_bhh[2 * H2 + j]);
    res2T[j * 64 + lane] = res1T[j * 64 + lane] + (1.0f - z) * nn;
}

// ---- Stage 10: out[0..10240) = res2 @ wout.T + bout  (n-major 64x160)
__global__ void k_out(const float* __restrict__ res2T, const float* __restrict__ wout,
                      const float* __restrict__ bout, float* __restrict__ out) {
    int i = rfl(blockIdx.x * 4 + (threadIdx.x >> 6));   // 0..159
    int lane = threadIdx.x & 63;
    const float* w = wout + (size_t)i * H2;
    float acc = 0.0f;
    #pragma unroll 16
    for (int k = 0; k < H2; ++k) acc += w[k] * res2T[k * 64 + lane];
    out[lane * 160 + i] = acc + bout[i];
}

extern "C" void kernel_launch(void* const* d_in, const int* in_sizes, int n_in,
                              void* d_out, int out_size, void* d_ws, size_t ws_size,
                              hipStream_t stream) {
    const float* input_enc      = (const float*)d_in[0];
    const float* input_attW_enc = (const float*)d_in[1];
    const float* input_dec      = (const float*)d_in[2];
    const float* style_vec      = (const float*)d_in[3];
    const int*   lengths_enc    = (const int*)d_in[4];
    const float* pw1  = (const float*)d_in[5];
    const float* pb1  = (const float*)d_in[6];
    const float* pw2  = (const float*)d_in[7];
    const float* pb2  = (const float*)d_in[8];
    const float* wdec = (const float*)d_in[9];
    const float* bdec = (const float*)d_in[10];
    const float* ga_ih  = (const float*)d_in[11];
    const float* ga_bih = (const float*)d_in[13];
    const float* ga_bhh = (const float*)d_in[14];
    const float* wattn  = (const float*)d_in[15];
    const float* battn  = (const float*)d_in[16];
    const float* wsc    = (const float*)d_in[17];
    const float* bsc    = (const float*)d_in[18];
    const float* g1_ih  = (const float*)d_in[19];
    const float* g1_bih = (const float*)d_in[21];
    const float* g1_bhh = (const float*)d_in[22];
    const float* g2_ih  = (const float*)d_in[23];
    const float* g2_bih = (const float*)d_in[25];
    const float* g2_bhh = (const float*)d_in[26];
    const float* wout   = (const float*)d_in[27];
    const float* bout   = (const float*)d_in[28];
    float* out = (float*)d_out;

    // workspace (floats); everything fully written before read — no zeroing needed
    float* ws = (float*)d_ws;
    float* num_part = ws;                         // CH*64*512 = 1048576
    float* den_part = ws + 1048576;               // CH*64    = 2048
    float* t1T      = ws + 1050624;               // 512*64   = 32768
    float* xaT      = ws + 1083392;               // 384*64   = 24576
    float* out_decT = ws + 1107968;               // 1152*64  = 73728
    float* attW_dec = ws + 1181696;               // 64*512   = 32768
    float* ew       = ws + 1214464;               // 64*1024  = 65536
    float* res1T    = ws + 1280000;               // 512*64   = 32768
    float* res2T    = ws + 1312768;               // 512*64   = 32768
    // total 1345536 floats = 5.4 MB

    k_l1<<<160, 256, 0, stream>>>(input_dec, pw1, pb1, style_vec, t1T, xaT, out_decT);
    k_l2<<<64, 256, 0, stream>>>(t1T, pw2, pb2, xaT);
    k_gruA<<<128, 256, 0, stream>>>(xaT, ga_ih, ga_bih, ga_bhh, out_decT);
    k_attw<<<128, 256, 0, stream>>>(out_decT, wdec, bdec, attW_dec);
    k_score<<<NB * TT / 4, 256, 0, stream>>>(input_attW_enc, attW_dec, wattn, battn,
                                             lengths_enc, ew);
    k_apply<<<dim3(CH, NB), 256, 0, stream>>>(input_enc, ew, num_part, den_part);
    k_reduce<<<128, 256, 0, stream>>>(num_part, den_part, out, out_decT);
    k_sc_h1<<<128, 256, 0, stream>>>(out_decT, wsc, bsc, g1_ih, g1_bih, g1_bhh, res1T);
    k_h2<<<128, 256, 0, stream>>>(res1T, g2_ih, g2_bih, g2_bhh, res2T);
    k_out<<<40, 256, 0, stream>>>(res2T, wout, bout, out);
}

// Round 4
// 401.052 us; speedup vs baseline: 1.3699x; 1.3699x over previous
//
#include <hip/hip_runtime.h>
#include <math.h>

#define NB  64
#define TT  1024
#define H2  512      // 2*H
#define SS  128      // style dim
#define OO  80
#define FIN_A 896    // 3H+S (ga_ih inner dim)
#define FIN_1 1152   // 4H+S (wsc / g1_ih inner dim)
#define CH  32       // t-chunks for apply (32 t per block, 8 per wave)

__device__ __forceinline__ float fast_rcp(float x) { return __builtin_amdgcn_rcpf(x); }
__device__ __forceinline__ float fast_sigmoid(float x) { return fast_rcp(1.0f + __expf(-x)); }
// tanh = 1 - 2/(e^{2x}+1); rcp(inf)=0 handles saturation
__device__ __forceinline__ float fast_tanh(float x) {
    float e = __expf(2.0f * x);
    return 1.0f - 2.0f * fast_rcp(e + 1.0f);
}
__device__ __forceinline__ float wred(float p) {
    #pragma unroll
    for (int o = 32; o > 0; o >>= 1) p += __shfl_xor(p, o, 64);
    return p;
}

// ---- Stage 1: t1T[i][n] = relu(input_dec @ pw1.T + pb1)^T ; blocks 128..159: svT copies
__global__ void k_l1(const float* __restrict__ xdec, const float* __restrict__ pw1,
                     const float* __restrict__ pb1, const float* __restrict__ sv,
                     float* __restrict__ t1T, float* __restrict__ xaT,
                     float* __restrict__ out_decT) {
    int wv = threadIdx.x >> 6, lane = threadIdx.x & 63;
    if (blockIdx.x < 128) {
        int i = blockIdx.x * 4 + wv;                 // 0..511
        const float* w = pw1 + i * OO;
        const float* x = xdec + lane * OO;
        float acc = 0.0f;
        #pragma unroll 8
        for (int k = 0; k < OO; ++k) acc += w[k] * x[k];
        t1T[i * 64 + lane] = fmaxf(acc + pb1[i], 0.0f);
    } else {
        int s = (blockIdx.x - 128) * 4 + wv;         // 0..127
        float v = sv[lane * SS + s];
        xaT[(256 + s) * 64 + lane] = v;              // sv rows of attention-GRU input
        out_decT[(1024 + s) * 64 + lane] = v;        // sv rows of out_dec
    }
}

// ---- Stage 2: xaT rows 0..255 = relu(t1 @ pw2.T + pb2)^T. Block per i; 4 waves split K=512.
__global__ void k_l2(const float* __restrict__ t1T, const float* __restrict__ pw2,
                     const float* __restrict__ pb2, float* __restrict__ xaT) {
    int i = blockIdx.x;                              // 0..255
    int wv = threadIdx.x >> 6, lane = threadIdx.x & 63;   // lane = n
    int k0 = wv * 128;
    const float* w = pw2 + (size_t)i * H2 + k0;
    const float* xT = t1T + k0 * 64;
    float p = 0.0f;
    #pragma unroll 8
    for (int k = 0; k < 128; ++k) p += w[k] * xT[k * 64 + lane];
    __shared__ float s[4][64];
    s[wv][lane] = p;
    __syncthreads();
    if (wv == 0) {
        float acc = s[0][lane] + s[1][lane] + s[2][lane] + s[3][lane];
        xaT[i * 64 + lane] = fmaxf(acc + pb2[i], 0.0f);
    }
}

// ---- Stage 3: attention GRU (h=0, ctx=0). Block per j; 4 waves split K=384 (3 gates).
__global__ void k_gruA(const float* __restrict__ xaT, const float* __restrict__ ga_ih,
                       const float* __restrict__ ga_bih, const float* __restrict__ ga_bhh,
                       float* __restrict__ out_decT) {
    int j = blockIdx.x;                              // 0..511
    int wv = threadIdx.x >> 6, lane = threadIdx.x & 63;
    int k0 = wv * 96;
    const float* wr = ga_ih + (size_t)j * FIN_A;
    const float* wz = ga_ih + (size_t)(H2 + j) * FIN_A;
    const float* wn = ga_ih + (size_t)(2 * H2 + j) * FIN_A;
    float pr = 0.0f, pz = 0.0f, pn = 0.0f;
    #pragma unroll 8
    for (int kk = 0; kk < 96; ++kk) {
        int k = k0 + kk;                             // xaT row
        int wc = k + (k >= 256 ? 512 : 0);           // weight col (sv lives at 768..895)
        float xv = xaT[k * 64 + lane];
        pr += wr[wc] * xv; pz += wz[wc] * xv; pn += wn[wc] * xv;
    }
    __shared__ float s[3][4][64];
    s[0][wv][lane] = pr; s[1][wv][lane] = pz; s[2][wv][lane] = pn;
    __syncthreads();
    if (wv == 0) {
        float fr = s[0][0][lane] + s[0][1][lane] + s[0][2][lane] + s[0][3][lane];
        float fz = s[1][0][lane] + s[1][1][lane] + s[1][2][lane] + s[1][3][lane];
        float fn = s[2][0][lane] + s[2][1][lane] + s[2][2][lane] + s[2][3][lane];
        float r = fast_sigmoid(fr + ga_bih[j] + ga_bhh[j]);
        float z = fast_sigmoid(fz + ga_bih[H2 + j] + ga_bhh[H2 + j]);
        float nn = fast_tanh(fn + ga_bih[2 * H2 + j] + r * ga_bhh[2 * H2 + j]);
        out_decT[(H2 + j) * 64 + lane] = (1.0f - z) * nn;
    }
}

// ---- Stage 4: attW_dec[n][i] = out_att @ wdec.T + bdec. Block per i; 4 waves split K=512.
__global__ void k_attw(const float* __restrict__ out_decT, const float* __restrict__ wdec,
                       const float* __restrict__ bdec, float* __restrict__ attW_dec) {
    int i = blockIdx.x;                              // 0..511
    int wv = threadIdx.x >> 6, lane = threadIdx.x & 63;
    int k0 = wv * 128;
    const float* w = wdec + (size_t)i * H2 + k0;
    const float* xT = out_decT + (H2 + k0) * 64;
    float p = 0.0f;
    #pragma unroll 8
    for (int k = 0; k < 128; ++k) p += w[k] * xT[k * 64 + lane];
    __shared__ float s[4][64];
    s[wv][lane] = p;
    __syncthreads();
    if (wv == 0) {
        float acc = s[0][lane] + s[1][lane] + s[2][lane] + s[3][lane];
        attW_dec[lane * H2 + i] = acc + bdec[i];     // scatter: 64 lines, 512 instrs total
    }
}

// ---- Stage 5: scores. Wave per (n,t); early-exit masked rows before any load.
__global__ void k_score(const float* __restrict__ attw_enc, const float* __restrict__ attW_dec,
                        const float* __restrict__ wattn, const float* __restrict__ battn,
                        const int* __restrict__ lengths, float* __restrict__ ew) {
    int wv = threadIdx.x >> 6, lane = threadIdx.x & 63;
    int row = blockIdx.x * 4 + wv;                  // n*1024 + t
    int n = row >> 10, t = row & 1023;
    if (t >= lengths[n]) { if (lane == 0) ew[row] = 0.0f; return; }
    const float4* e4 = (const float4*)(attw_enc + (size_t)row * H2);
    const float4* d4 = (const float4*)(attW_dec + n * H2);
    const float4* w4 = (const float4*)wattn;
    float p = 0.0f;
    #pragma unroll
    for (int m = 0; m < 2; ++m) {
        int idx = lane + m * 64;
        float4 e = e4[idx], d = d4[idx], w = w4[idx];
        p += fast_tanh(e.x + d.x) * w.x + fast_tanh(e.y + d.y) * w.y +
             fast_tanh(e.z + d.z) * w.z + fast_tanh(e.w + d.w) * w.w;
    }
    p = wred(p);
    if (lane == 0) ew[row] = __expf(p + battn[0]);
}

// ---- Stage 6: weighted-sum partials. Block (c,n); skip zero-weight rows.
// num_part layout [c][dim][n] so the reducer reads coalesced.
__global__ void k_apply(const float* __restrict__ enc, const float* __restrict__ ew,
                        float* __restrict__ num_part /*[CH][512][64]*/,
                        float* __restrict__ den_part /*[CH][NB]*/) {
    int n = blockIdx.y, c = blockIdx.x;
    int wv = threadIdx.x >> 6, lane = threadIdx.x & 63;
    int t0 = c * (TT / CH) + wv * (TT / CH / 4);
    int d0 = lane * 8;
    const float* base = enc + ((size_t)n * TT + t0) * H2 + d0;
    const float* ewp = ew + n * TT + t0;
    float4 a0 = {0, 0, 0, 0}, a1 = {0, 0, 0, 0};
    float dp = 0.0f;
    #pragma unroll
    for (int t = 0; t < TT / CH / 4; ++t) {
        float wt = ewp[t];
        if (wt != 0.0f) {                            // wave-uniform skip of masked rows
            const float4* v4 = (const float4*)(base + (size_t)t * H2);
            float4 v0 = v4[0], v1 = v4[1];
            a0.x += wt * v0.x; a0.y += wt * v0.y; a0.z += wt * v0.z; a0.w += wt * v0.w;
            a1.x += wt * v1.x; a1.y += wt * v1.y; a1.z += wt * v1.z; a1.w += wt * v1.w;
            dp += wt;
        }
    }
    __shared__ float s[4 * 512];
    __shared__ float sd[4];
    float4* srow = (float4*)(s + wv * 512 + d0);
    srow[0] = a0; srow[1] = a1;
    if (lane == 0) sd[wv] = dp;
    __syncthreads();
    int d = threadIdx.x;
    float r0 = s[d] + s[512 + d] + s[1024 + d] + s[1536 + d];
    float r1 = s[256 + d] + s[768 + d] + s[1280 + d] + s[1792 + d];
    num_part[((size_t)c * H2 + d) * 64 + n] = r0;
    num_part[((size_t)c * H2 + 256 + d) * 64 + n] = r1;
    if (threadIdx.x == 0) den_part[c * NB + n] = sd[0] + sd[1] + sd[2] + sd[3];
}

// ---- Stage 7: reduce partials; write attn_applied (output 1) + out_decT rows 0..511
__global__ void k_reduce(const float* __restrict__ num_part, const float* __restrict__ den_part,
                         float* __restrict__ out, float* __restrict__ out_decT) {
    int d = blockIdx.x * 4 + (threadIdx.x >> 6);    // 0..511
    int lane = threadIdx.x & 63;                    // n
    float s = 0.0f, den = 0.0f;
    #pragma unroll 8
    for (int c = 0; c < CH; ++c) {
        s += num_part[((size_t)c * H2 + d) * 64 + lane];
        den += den_part[c * NB + lane];
    }
    float a = s / fmaxf(den, 1e-12f);
    out_decT[d * 64 + lane] = a;
    out[NB * 160 + lane * H2 + d] = a;              // output 1: attn_applied (n-major)
}

// ---- Stage 8: res1T = (out_dec @ wsc.T + bsc + GRU1(out_dec,0))^T. Block per j; 4 waves split K=1152.
__global__ void k_sc_h1(const float* __restrict__ out_decT, const float* __restrict__ wsc,
                        const float* __restrict__ bsc, const float* __restrict__ g1_ih,
                        const float* __restrict__ g1_bih, const float* __restrict__ g1_bhh,
                        float* __restrict__ res1T) {
    int j = blockIdx.x;                              // 0..511
    int wv = threadIdx.x >> 6, lane = threadIdx.x & 63;
    int k0 = wv * 288;
    const float* ws_ = wsc + (size_t)j * FIN_1 + k0;
    const float* wr = g1_ih + (size_t)j * FIN_1 + k0;
    const float* wz = g1_ih + (size_t)(H2 + j) * FIN_1 + k0;
    const float* wn = g1_ih + (size_t)(2 * H2 + j) * FIN_1 + k0;
    const float* xT = out_decT + k0 * 64;
    float ps = 0.0f, pr = 0.0f, pz = 0.0f, pn = 0.0f;
    #pragma unroll 8
    for (int k = 0; k < 288; ++k) {
        float xv = xT[k * 64 + lane];
        ps += ws_[k] * xv; pr += wr[k] * xv; pz += wz[k] * xv; pn += wn[k] * xv;
    }
    __shared__ float s[4][4][64];
    s[0][wv][lane] = ps; s[1][wv][lane] = pr; s[2][wv][lane] = pz; s[3][wv][lane] = pn;
    __syncthreads();
    if (wv == 0) {
        float fs = s[0][0][lane] + s[0][1][lane] + s[0][2][lane] + s[0][3][lane];
        float fr = s[1][0][lane] + s[1][1][lane] + s[1][2][lane] + s[1][3][lane];
        float fz = s[2][0][lane] + s[2][1][lane] + s[2][2][lane] + s[2][3][lane];
        float fn = s[3][0][lane] + s[3][1][lane] + s[3][2][lane] + s[3][3][lane];
        float r = fast_sigmoid(fr + g1_bih[j] + g1_bhh[j]);
        float z = fast_sigmoid(fz + g1_bih[H2 + j] + g1_bhh[H2 + j]);
        float nn = fast_tanh(fn + g1_bih[2 * H2 + j] + r * g1_bhh[2 * H2 + j]);
        res1T[j * 64 + lane] = fs + bsc[j] + (1.0f - z) * nn;
    }
}

// ---- Stage 9: res2T = res1T + GRU2(res1,0)^T. Block per j; 4 waves split K=512.
__global__ void k_h2(const float* __restrict__ res1T, const float* __restrict__ g2_ih,
                     const float* __restrict__ g2_bih, const float* __restrict__ g2_bhh,
                     float* __restrict__ res2T) {
    int j = blockIdx.x;                              // 0..511
    int wv = threadIdx.x >> 6, lane = threadIdx.x & 63;
    int k0 = wv * 128;
    const float* wr = g2_ih + (size_t)j * H2 + k0;
    const float* wz = g2_ih + (size_t)(H2 + j) * H2 + k0;
    const float* wn = g2_ih + (size_t)(2 * H2 + j) * H2 + k0;
    const float* xT = res1T + k0 * 64;
    float pr = 0.0f, pz = 0.0f, pn = 0.0f;
    #pragma unroll 8
    for (int k = 0; k < 128; ++k) {
        float xv = xT[k * 64 + lane];
        pr += wr[k] * xv; pz += wz[k] * xv; pn += wn[k] * xv;
    }
    __shared__ float s[3][4][64];
    s[0][wv][lane] = pr; s[1][wv][lane] = pz; s[2][wv][lane] = pn;
    __syncthreads();
    if (wv == 0) {
        float fr = s[0][0][lane] + s[0][1][lane] + s[0][2][lane] + s[0][3][lane];
        float fz = s[1][0][lane] + s[1][1][lane] + s[1][2][lane] + s[1][3][lane];
        float fn = s[2][0][lane] + s[2][1][lane] + s[2][2][lane] + s[2][3][lane];
        float r = fast_sigmoid(fr + g2_bih[j] + g2_bhh[j]);
        float z = fast_sigmoid(fz + g2_bih[H2 + j] + g2_bhh[H2 + j]);
        float nn = fast_tanh(fn + g2_bih[2 * H2 + j] + r * g2_bhh[2 * H2 + j]);
        res2T[j * 64 + lane] = res1T[j * 64 + lane] + (1.0f - z) * nn;
    }
}

// ---- Stage 10: out[0..10240) = res2 @ wout.T + bout. Block per i; 4 waves split K=512.
__global__ void k_out(const float* __restrict__ res2T, const float* __restrict__ wout,
                      const float* __restrict__ bout, float* __restrict__ out) {
    int i = blockIdx.x;                              // 0..159
    int wv = threadIdx.x >> 6, lane = threadIdx.x & 63;
    int k0 = wv * 128;
    const float* w = wout + (size_t)i * H2 + k0;
    const float* xT = res2T + k0 * 64;
    float p = 0.0f;
    #pragma unroll 8
    for (int k = 0; k < 128; ++k) p += w[k] * xT[k * 64 + lane];
    __shared__ float s[4][64];
    s[wv][lane] = p;
    __syncthreads();
    if (wv == 0) {
        float acc = s[0][lane] + s[1][lane] + s[2][lane] + s[3][lane];
        out[lane * 160 + i] = acc + bout[i];
    }
}

extern "C" void kernel_launch(void* const* d_in, const int* in_sizes, int n_in,
                              void* d_out, int out_size, void* d_ws, size_t ws_size,
                              hipStream_t stream) {
    const float* input_enc      = (const float*)d_in[0];
    const float* input_attW_enc = (const float*)d_in[1];
    const float* input_dec      = (const float*)d_in[2];
    const float* style_vec      = (const float*)d_in[3];
    const int*   lengths_enc    = (const int*)d_in[4];
    const float* pw1  = (const float*)d_in[5];
    const float* pb1  = (const float*)d_in[6];
    const float* pw2  = (const float*)d_in[7];
    const float* pb2  = (const float*)d_in[8];
    const float* wdec = (const float*)d_in[9];
    const float* bdec = (const float*)d_in[10];
    const float* ga_ih  = (const float*)d_in[11];
    const float* ga_bih = (const float*)d_in[13];
    const float* ga_bhh = (const float*)d_in[14];
    const float* wattn  = (const float*)d_in[15];
    const float* battn  = (const float*)d_in[16];
    const float* wsc    = (const float*)d_in[17];
    const float* bsc    = (const float*)d_in[18];
    const float* g1_ih  = (const float*)d_in[19];
    const float* g1_bih = (const float*)d_in[21];
    const float* g1_bhh = (const float*)d_in[22];
    const float* g2_ih  = (const float*)d_in[23];
    const float* g2_bih = (const float*)d_in[25];
    const float* g2_bhh = (const float*)d_in[26];
    const float* wout   = (const float*)d_in[27];
    const float* bout   = (const float*)d_in[28];
    float* out = (float*)d_out;

    // workspace (floats); everything fully written before read — no zeroing needed
    float* ws = (float*)d_ws;
    float* num_part = ws;                         // CH*512*64 = 1048576
    float* den_part = ws + 1048576;               // CH*64    = 2048
    float* t1T      = ws + 1050624;               // 512*64   = 32768
    float* xaT      = ws + 1083392;               // 384*64   = 24576
    float* out_decT = ws + 1107968;               // 1152*64  = 73728
    float* attW_dec = ws + 1181696;               // 64*512   = 32768
    float* ew       = ws + 1214464;               // 64*1024  = 65536
    float* res1T    = ws + 1280000;               // 512*64   = 32768
    float* res2T    = ws + 1312768;               // 512*64   = 32768

    k_l1<<<160, 256, 0, stream>>>(input_dec, pw1, pb1, style_vec, t1T, xaT, out_decT);
    k_l2<<<256, 256, 0, stream>>>(t1T, pw2, pb2, xaT);
    k_gruA<<<512, 256, 0, stream>>>(xaT, ga_ih, ga_bih, ga_bhh, out_decT);
    k_attw<<<512, 256, 0, stream>>>(out_decT, wdec, bdec, attW_dec);
    k_score<<<NB * TT / 4, 256, 0, stream>>>(input_attW_enc, attW_dec, wattn, battn,
                                             lengths_enc, ew);
    k_apply<<<dim3(CH, NB), 256, 0, stream>>>(input_enc, ew, num_part, den_part);
    k_reduce<<<128, 256, 0, stream>>>(num_part, den_part, out, out_decT);
    k_sc_h1<<<512, 256, 0, stream>>>(out_decT, wsc, bsc, g1_ih, g1_bih, g1_bhh, res1T);
    k_h2<<<512, 256, 0, stream>>>(res1T, g2_ih, g2_bih, g2_bhh, res2T);
    k_out<<<160, 256, 0, stream>>>(res2T, wout, bout, out);
}

// Round 5
// 388.388 us; speedup vs baseline: 1.4146x; 1.0326x over previous
//
#include <hip/hip_runtime.h>
#include <math.h>

#define NB  64
#define TT  1024
#define H2  512      // 2*H
#define SS  128      // style dim
#define OO  80
#define FIN_A 896    // 3H+S (ga_ih inner dim)
#define FIN_1 1152   // 4H+S (wsc / g1_ih inner dim)
#define CH  32       // t-chunks for fused attention (32 t per block, 8 per wave)

__device__ __forceinline__ float fast_rcp(float x) { return __builtin_amdgcn_rcpf(x); }
__device__ __forceinline__ float fast_sigmoid(float x) { return fast_rcp(1.0f + __expf(-x)); }
// tanh = 1 - 2/(e^{2x}+1); rcp(inf)=0 handles saturation
__device__ __forceinline__ float fast_tanh(float x) {
    float e = __expf(2.0f * x);
    return 1.0f - 2.0f * fast_rcp(e + 1.0f);
}
__device__ __forceinline__ float wred(float p) {
    #pragma unroll
    for (int o = 32; o > 0; o >>= 1) p += __shfl_xor(p, o, 64);
    return p;
}

// ---- Stage 1: t1T[i][n] = relu(input_dec @ pw1.T + pb1)^T ; blocks 128..159: svT copies
__global__ void k_l1(const float* __restrict__ xdec, const float* __restrict__ pw1,
                     const float* __restrict__ pb1, const float* __restrict__ sv,
                     float* __restrict__ t1T, float* __restrict__ xaT,
                     float* __restrict__ out_decT) {
    int wv = threadIdx.x >> 6, lane = threadIdx.x & 63;
    if (blockIdx.x < 128) {
        int i = blockIdx.x * 4 + wv;                 // 0..511
        const float* w = pw1 + i * OO;
        const float* x = xdec + lane * OO;
        float acc = 0.0f;
        #pragma unroll 8
        for (int k = 0; k < OO; ++k) acc += w[k] * x[k];
        t1T[i * 64 + lane] = fmaxf(acc + pb1[i], 0.0f);
    } else {
        int s = (blockIdx.x - 128) * 4 + wv;         // 0..127
        float v = sv[lane * SS + s];
        xaT[(256 + s) * 64 + lane] = v;              // sv rows of attention-GRU input
        out_decT[(1024 + s) * 64 + lane] = v;        // sv rows of out_dec
    }
}

// ---- Stage 2: xaT rows 0..255 = relu(t1 @ pw2.T + pb2)^T. Block per i; 8 waves split K=512.
__global__ __launch_bounds__(512) void k_l2(const float* __restrict__ t1T,
                                            const float* __restrict__ pw2,
                                            const float* __restrict__ pb2,
                                            float* __restrict__ xaT) {
    int i = blockIdx.x;                              // 0..255
    int wv = threadIdx.x >> 6, lane = threadIdx.x & 63;   // lane = n
    int k0 = wv * 64;
    const float* w = pw2 + (size_t)i * H2 + k0;
    const float* xT = t1T + k0 * 64;
    float p = 0.0f;
    #pragma unroll 8
    for (int k = 0; k < 64; ++k) p += w[k] * xT[k * 64 + lane];
    __shared__ float s[8][64];
    s[wv][lane] = p;
    __syncthreads();
    if (wv == 0) {
        float acc = 0.0f;
        #pragma unroll
        for (int q = 0; q < 8; ++q) acc += s[q][lane];
        xaT[i * 64 + lane] = fmaxf(acc + pb2[i], 0.0f);
    }
}

// ---- Stage 3: attention GRU (h=0, ctx=0). Block per j; 8 waves split K=384 (3 gates).
__global__ __launch_bounds__(512) void k_gruA(const float* __restrict__ xaT,
                                              const float* __restrict__ ga_ih,
                                              const float* __restrict__ ga_bih,
                                              const float* __restrict__ ga_bhh,
                                              float* __restrict__ out_decT) {
    int j = blockIdx.x;                              // 0..511
    int wv = threadIdx.x >> 6, lane = threadIdx.x & 63;
    int k0 = wv * 48;
    const float* wr = ga_ih + (size_t)j * FIN_A;
    const float* wz = ga_ih + (size_t)(H2 + j) * FIN_A;
    const float* wn = ga_ih + (size_t)(2 * H2 + j) * FIN_A;
    float pr = 0.0f, pz = 0.0f, pn = 0.0f;
    #pragma unroll 8
    for (int kk = 0; kk < 48; ++kk) {
        int k = k0 + kk;                             // xaT row
        int wc = k + (k >= 256 ? 512 : 0);           // weight col (sv lives at 768..895)
        float xv = xaT[k * 64 + lane];
        pr += wr[wc] * xv; pz += wz[wc] * xv; pn += wn[wc] * xv;
    }
    __shared__ float s[3][8][64];
    s[0][wv][lane] = pr; s[1][wv][lane] = pz; s[2][wv][lane] = pn;
    __syncthreads();
    if (wv == 0) {
        float fr = 0.0f, fz = 0.0f, fn = 0.0f;
        #pragma unroll
        for (int q = 0; q < 8; ++q) { fr += s[0][q][lane]; fz += s[1][q][lane]; fn += s[2][q][lane]; }
        float r = fast_sigmoid(fr + ga_bih[j] + ga_bhh[j]);
        float z = fast_sigmoid(fz + ga_bih[H2 + j] + ga_bhh[H2 + j]);
        float nn = fast_tanh(fn + ga_bih[2 * H2 + j] + r * ga_bhh[2 * H2 + j]);
        out_decT[(H2 + j) * 64 + lane] = (1.0f - z) * nn;
    }
}

// ---- Stage 4: attW_dec[n][i] = out_att @ wdec.T + bdec. Block per i; 8 waves split K=512.
__global__ __launch_bounds__(512) void k_attw(const float* __restrict__ out_decT,
                                              const float* __restrict__ wdec,
                                              const float* __restrict__ bdec,
                                              float* __restrict__ attW_dec) {
    int i = blockIdx.x;                              // 0..511
    int wv = threadIdx.x >> 6, lane = threadIdx.x & 63;
    int k0 = wv * 64;
    const float* w = wdec + (size_t)i * H2 + k0;
    const float* xT = out_decT + (H2 + k0) * 64;
    float p = 0.0f;
    #pragma unroll 8
    for (int k = 0; k < 64; ++k) p += w[k] * xT[k * 64 + lane];
    __shared__ float s[8][64];
    s[wv][lane] = p;
    __syncthreads();
    if (wv == 0) {
        float acc = 0.0f;
        #pragma unroll
        for (int q = 0; q < 8; ++q) acc += s[q][lane];
        attW_dec[lane * H2 + i] = acc + bdec[i];
    }
}

// ---- Stage 5: FUSED score+apply. Block (c,n): phase 1 computes 32 scores -> LDS,
// phase 2 streams enc with weights from LDS. No ew array, den from LDS sum.
__global__ __launch_bounds__(256, 8) void k_attn(
        const float* __restrict__ enc, const float* __restrict__ attw_enc,
        const float* __restrict__ attW_dec, const float* __restrict__ wattn,
        const float* __restrict__ battn, const int* __restrict__ lengths,
        float* __restrict__ num_part /*[CH][512][64]*/,
        float* __restrict__ den_part /*[CH][NB]*/) {
    int n = blockIdx.y, c = blockIdx.x;
    int wv = threadIdx.x >> 6, lane = threadIdx.x & 63;
    int t0 = c * (TT / CH);
    int len = lengths[n];
    __shared__ float sew[TT / CH];
    __shared__ float s[4 * 512];
    __shared__ float sd[4];

    // phase 1: scores for rows t0+wv*8 .. +8
    {
        const float4* d4 = (const float4*)(attW_dec + n * H2);
        const float4* w4 = (const float4*)wattn;
        float b = battn[0];
        #pragma unroll
        for (int r = 0; r < 8; ++r) {
            int t = t0 + wv * 8 + r;
            float val = 0.0f;
            if (t < len) {                           // wave-uniform
                const float4* e4 = (const float4*)(attw_enc + ((size_t)(n * TT + t)) * H2);
                float p = 0.0f;
                #pragma unroll
                for (int m = 0; m < 2; ++m) {
                    int idx = lane + m * 64;
                    float4 e = e4[idx], d = d4[idx], w = w4[idx];
                    p += fast_tanh(e.x + d.x) * w.x + fast_tanh(e.y + d.y) * w.y +
                         fast_tanh(e.z + d.z) * w.z + fast_tanh(e.w + d.w) * w.w;
                }
                p = wred(p);
                val = __expf(p + b);
            }
            if (lane == 0) sew[wv * 8 + r] = val;
        }
    }
    __syncthreads();

    // phase 2: weighted accumulate over the same 8 rows per wave
    int d0 = lane * 8;
    const float* base = enc + ((size_t)(n * TT + t0 + wv * 8)) * H2 + d0;
    float4 a0 = {0, 0, 0, 0}, a1 = {0, 0, 0, 0};
    float dp = 0.0f;
    #pragma unroll
    for (int r = 0; r < 8; ++r) {
        float wt = sew[wv * 8 + r];
        if (wt != 0.0f) {                            // wave-uniform skip
            const float4* v4 = (const float4*)(base + (size_t)r * H2);
            float4 v0 = v4[0], v1 = v4[1];
            a0.x += wt * v0.x; a0.y += wt * v0.y; a0.z += wt * v0.z; a0.w += wt * v0.w;
            a1.x += wt * v1.x; a1.y += wt * v1.y; a1.z += wt * v1.z; a1.w += wt * v1.w;
            dp += wt;
        }
    }
    float4* srow = (float4*)(s + wv * 512 + d0);
    srow[0] = a0; srow[1] = a1;
    if (lane == 0) sd[wv] = dp;
    __syncthreads();
    int d = threadIdx.x;
    float r0 = s[d] + s[512 + d] + s[1024 + d] + s[1536 + d];
    float r1 = s[256 + d] + s[768 + d] + s[1280 + d] + s[1792 + d];
    num_part[((size_t)c * H2 + d) * 64 + n] = r0;
    num_part[((size_t)c * H2 + 256 + d) * 64 + n] = r1;
    if (threadIdx.x == 0) den_part[c * NB + n] = sd[0] + sd[1] + sd[2] + sd[3];
}

// ---- Stage 6: reduce partials; write attn_applied (output 1) + out_decT rows 0..511
__global__ void k_reduce(const float* __restrict__ num_part, const float* __restrict__ den_part,
                         float* __restrict__ out, float* __restrict__ out_decT) {
    int d = blockIdx.x * 4 + (threadIdx.x >> 6);    // 0..511
    int lane = threadIdx.x & 63;                    // n
    float s = 0.0f, den = 0.0f;
    #pragma unroll 8
    for (int c = 0; c < CH; ++c) {
        s += num_part[((size_t)c * H2 + d) * 64 + lane];
        den += den_part[c * NB + lane];
    }
    float a = s / fmaxf(den, 1e-12f);
    out_decT[d * 64 + lane] = a;
    out[NB * 160 + lane * H2 + d] = a;              // output 1: attn_applied (n-major)
}

// ---- Stage 7: res1T = (out_dec @ wsc.T + bsc + GRU1(out_dec,0))^T. Block per j; 8 waves split K=1152.
__global__ __launch_bounds__(512) void k_sc_h1(const float* __restrict__ out_decT,
                                               const float* __restrict__ wsc,
                                               const float* __restrict__ bsc,
                                               const float* __restrict__ g1_ih,
                                               const float* __restrict__ g1_bih,
                                               const float* __restrict__ g1_bhh,
                                               float* __restrict__ res1T) {
    int j = blockIdx.x;                              // 0..511
    int wv = threadIdx.x >> 6, lane = threadIdx.x & 63;
    int k0 = wv * 144;
    const float* ws_ = wsc + (size_t)j * FIN_1 + k0;
    const float* wr = g1_ih + (size_t)j * FIN_1 + k0;
    const float* wz = g1_ih + (size_t)(H2 + j) * FIN_1 + k0;
    const float* wn = g1_ih + (size_t)(2 * H2 + j) * FIN_1 + k0;
    const float* xT = out_decT + k0 * 64;
    // float2 k-pairing to invite v_pk_fma_f32
    float2 ps = {0, 0}, pr = {0, 0}, pz = {0, 0}, pn = {0, 0};
    #pragma unroll 4
    for (int k = 0; k < 144; k += 2) {
        float x0 = xT[k * 64 + lane];
        float x1 = xT[(k + 1) * 64 + lane];
        float2 a = *(const float2*)(ws_ + k);
        float2 b = *(const float2*)(wr + k);
        float2 cc = *(const float2*)(wz + k);
        float2 dd = *(const float2*)(wn + k);
        ps.x += a.x * x0; ps.y += a.y * x1;
        pr.x += b.x * x0; pr.y += b.y * x1;
        pz.x += cc.x * x0; pz.y += cc.y * x1;
        pn.x += dd.x * x0; pn.y += dd.y * x1;
    }
    __shared__ float s[4][8][64];
    s[0][wv][lane] = ps.x + ps.y; s[1][wv][lane] = pr.x + pr.y;
    s[2][wv][lane] = pz.x + pz.y; s[3][wv][lane] = pn.x + pn.y;
    __syncthreads();
    if (wv == 0) {
        float fs = 0.0f, fr = 0.0f, fz = 0.0f, fn = 0.0f;
        #pragma unroll
        for (int q = 0; q < 8; ++q) {
            fs += s[0][q][lane]; fr += s[1][q][lane];
            fz += s[2][q][lane]; fn += s[3][q][lane];
        }
        float r = fast_sigmoid(fr + g1_bih[j] + g1_bhh[j]);
        float z = fast_sigmoid(fz + g1_bih[H2 + j] + g1_bhh[H2 + j]);
        float nn = fast_tanh(fn + g1_bih[2 * H2 + j] + r * g1_bhh[2 * H2 + j]);
        res1T[j * 64 + lane] = fs + bsc[j] + (1.0f - z) * nn;
    }
}

// ---- Stage 8: res2T = res1T + GRU2(res1,0)^T. Block per j; 8 waves split K=512.
__global__ __launch_bounds__(512) void k_h2(const float* __restrict__ res1T,
                                            const float* __restrict__ g2_ih,
                                            const float* __restrict__ g2_bih,
                                            const float* __restrict__ g2_bhh,
                                            float* __restrict__ res2T) {
    int j = blockIdx.x;                              // 0..511
    int wv = threadIdx.x >> 6, lane = threadIdx.x & 63;
    int k0 = wv * 64;
    const float* wr = g2_ih + (size_t)j * H2 + k0;
    const float* wz = g2_ih + (size_t)(H2 + j) * H2 + k0;
    const float* wn = g2_ih + (size_t)(2 * H2 + j) * H2 + k0;
    const float* xT = res1T + k0 * 64;
    float pr = 0.0f, pz = 0.0f, pn = 0.0f;
    #pragma unroll 8
    for (int k = 0; k < 64; ++k) {
        float xv = xT[k * 64 + lane];
        pr += wr[k] * xv; pz += wz[k] * xv; pn += wn[k] * xv;
    }
    __shared__ float s[3][8][64];
    s[0][wv][lane] = pr; s[1][wv][lane] = pz; s[2][wv][lane] = pn;
    __syncthreads();
    if (wv == 0) {
        float fr = 0.0f, fz = 0.0f, fn = 0.0f;
        #pragma unroll
        for (int q = 0; q < 8; ++q) { fr += s[0][q][lane]; fz += s[1][q][lane]; fn += s[2][q][lane]; }
        float r = fast_sigmoid(fr + g2_bih[j] + g2_bhh[j]);
        float z = fast_sigmoid(fz + g2_bih[H2 + j] + g2_bhh[H2 + j]);
        float nn = fast_tanh(fn + g2_bih[2 * H2 + j] + r * g2_bhh[2 * H2 + j]);
        res2T[j * 64 + lane] = res1T[j * 64 + lane] + (1.0f - z) * nn;
    }
}

// ---- Stage 9: out[0..10240) = res2 @ wout.T + bout. Block per i; 8 waves split K=512.
__global__ __launch_bounds__(512) void k_out(const float* __restrict__ res2T,
                                             const float* __restrict__ wout,
                                             const float* __restrict__ bout,
                                             float* __restrict__ out) {
    int i = blockIdx.x;                              // 0..159
    int wv = threadIdx.x >> 6, lane = threadIdx.x & 63;
    int k0 = wv * 64;
    const float* w = wout + (size_t)i * H2 + k0;
    const float* xT = res2T + k0 * 64;
    float p = 0.0f;
    #pragma unroll 8
    for (int k = 0; k < 64; ++k) p += w[k] * xT[k * 64 + lane];
    __shared__ float s[8][64];
    s[wv][lane] = p;
    __syncthreads();
    if (wv == 0) {
        float acc = 0.0f;
        #pragma unroll
        for (int q = 0; q < 8; ++q) acc += s[q][lane];
        out[lane * 160 + i] = acc + bout[i];
    }
}

extern "C" void kernel_launch(void* const* d_in, const int* in_sizes, int n_in,
                              void* d_out, int out_size, void* d_ws, size_t ws_size,
                              hipStream_t stream) {
    const float* input_enc      = (const float*)d_in[0];
    const float* input_attW_enc = (const float*)d_in[1];
    const float* input_dec      = (const float*)d_in[2];
    const float* style_vec      = (const float*)d_in[3];
    const int*   lengths_enc    = (const int*)d_in[4];
    const float* pw1  = (const float*)d_in[5];
    const float* pb1  = (const float*)d_in[6];
    const float* pw2  = (const float*)d_in[7];
    const float* pb2  = (const float*)d_in[8];
    const float* wdec = (const float*)d_in[9];
    const float* bdec = (const float*)d_in[10];
    const float* ga_ih  = (const float*)d_in[11];
    const float* ga_bih = (const float*)d_in[13];
    const float* ga_bhh = (const float*)d_in[14];
    const float* wattn  = (const float*)d_in[15];
    const float* battn  = (const float*)d_in[16];
    const float* wsc    = (const float*)d_in[17];
    const float* bsc    = (const float*)d_in[18];
    const float* g1_ih  = (const float*)d_in[19];
    const float* g1_bih = (const float*)d_in[21];
    const float* g1_bhh = (const float*)d_in[22];
    const float* g2_ih  = (const float*)d_in[23];
    const float* g2_bih = (const float*)d_in[25];
    const float* g2_bhh = (const float*)d_in[26];
    const float* wout   = (const float*)d_in[27];
    const float* bout   = (const float*)d_in[28];
    float* out = (float*)d_out;

    // workspace (floats); everything fully written before read — no zeroing needed
    float* ws = (float*)d_ws;
    float* num_part = ws;                         // CH*512*64 = 1048576
    float* den_part = ws + 1048576;               // CH*64    = 2048
    float* t1T      = ws + 1050624;               // 512*64   = 32768
    float* xaT      = ws + 1083392;               // 384*64   = 24576
    float* out_decT = ws + 1107968;               // 1152*64  = 73728
    float* attW_dec = ws + 1181696;               // 64*512   = 32768
    float* res1T    = ws + 1214464;               // 512*64   = 32768
    float* res2T    = ws + 1247232;               // 512*64   = 32768

    k_l1<<<160, 256, 0, stream>>>(input_dec, pw1, pb1, style_vec, t1T, xaT, out_decT);
    k_l2<<<256, 512, 0, stream>>>(t1T, pw2, pb2, xaT);
    k_gruA<<<512, 512, 0, stream>>>(xaT, ga_ih, ga_bih, ga_bhh, out_decT);
    k_attw<<<512, 512, 0, stream>>>(out_decT, wdec, bdec, attW_dec);
    k_attn<<<dim3(CH, NB), 256, 0, stream>>>(input_enc, input_attW_enc, attW_dec,
                                             wattn, battn, lengths_enc, num_part, den_part);
    k_reduce<<<128, 256, 0, stream>>>(num_part, den_part, out, out_decT);
    k_sc_h1<<<512, 512, 0, stream>>>(out_decT, wsc, bsc, g1_ih, g1_bih, g1_bhh, res1T);
    k_h2<<<512, 512, 0, stream>>>(res1T, g2_ih, g2_bih, g2_bhh, res2T);
    k_out<<<160, 512, 0, stream>>>(res2T, wout, bout, out);
}

// Round 6
// 383.326 us; speedup vs baseline: 1.4333x; 1.0132x over previous
//
#include <hip/hip_runtime.h>
#include <math.h>

#define NB  64
#define TT  1024
#define H2  512      // 2*H
#define SS  128      // style dim
#define OO  80
#define FIN_A 896    // 3H+S (ga_ih inner dim)
#define FIN_1 1152   // 4H+S (wsc / g1_ih inner dim)
#define CH  32       // t-chunks for fused attention (32 t per chunk, 8 per wave)

__device__ __forceinline__ float fast_rcp(float x) { return __builtin_amdgcn_rcpf(x); }
__device__ __forceinline__ float fast_sigmoid(float x) { return fast_rcp(1.0f + __expf(-x)); }
// tanh = 1 - 2/(e^{2x}+1); rcp(inf)=0 handles saturation
__device__ __forceinline__ float fast_tanh(float x) {
    float e = __expf(2.0f * x);
    return 1.0f - 2.0f * fast_rcp(e + 1.0f);
}
__device__ __forceinline__ float wred(float p) {
    #pragma unroll
    for (int o = 32; o > 0; o >>= 1) p += __shfl_xor(p, o, 64);
    return p;
}

// ---- Stage 1: t1T[i][n] = relu(input_dec @ pw1.T + pb1)^T ; blocks 128..159: svT copies
__global__ void k_l1(const float* __restrict__ xdec, const float* __restrict__ pw1,
                     const float* __restrict__ pb1, const float* __restrict__ sv,
                     float* __restrict__ t1T, float* __restrict__ xaT,
                     float* __restrict__ out_decT) {
    int wv = threadIdx.x >> 6, lane = threadIdx.x & 63;
    if (blockIdx.x < 128) {
        int i = blockIdx.x * 4 + wv;                 // 0..511
        const float* w = pw1 + i * OO;
        const float* x = xdec + lane * OO;
        float acc = 0.0f;
        #pragma unroll 8
        for (int k = 0; k < OO; ++k) acc += w[k] * x[k];
        t1T[i * 64 + lane] = fmaxf(acc + pb1[i], 0.0f);
    } else {
        int s = (blockIdx.x - 128) * 4 + wv;         // 0..127
        float v = sv[lane * SS + s];
        xaT[(256 + s) * 64 + lane] = v;              // sv rows of attention-GRU input
        out_decT[(1024 + s) * 64 + lane] = v;        // sv rows of out_dec
    }
}

// ---- Stage 2: xaT rows 0..255 = relu(t1 @ pw2.T + pb2)^T. Block per i; 8 waves split K=512.
__global__ __launch_bounds__(512) void k_l2(const float* __restrict__ t1T,
                                            const float* __restrict__ pw2,
                                            const float* __restrict__ pb2,
                                            float* __restrict__ xaT) {
    int i = blockIdx.x;                              // 0..255
    int wv = threadIdx.x >> 6, lane = threadIdx.x & 63;   // lane = n
    int k0 = wv * 64;
    const float* w = pw2 + (size_t)i * H2 + k0;
    const float* xT = t1T + k0 * 64;
    float p = 0.0f;
    #pragma unroll 8
    for (int k = 0; k < 64; ++k) p += w[k] * xT[k * 64 + lane];
    __shared__ float s[8][64];
    s[wv][lane] = p;
    __syncthreads();
    if (wv == 0) {
        float acc = 0.0f;
        #pragma unroll
        for (int q = 0; q < 8; ++q) acc += s[q][lane];
        xaT[i * 64 + lane] = fmaxf(acc + pb2[i], 0.0f);
    }
}

// ---- Stage 3: attention GRU (h=0, ctx=0). Block per j; 8 waves split K=384 (3 gates).
__global__ __launch_bounds__(512) void k_gruA(const float* __restrict__ xaT,
                                              const float* __restrict__ ga_ih,
                                              const float* __restrict__ ga_bih,
                                              const float* __restrict__ ga_bhh,
                                              float* __restrict__ out_decT) {
    int j = blockIdx.x;                              // 0..511
    int wv = threadIdx.x >> 6, lane = threadIdx.x & 63;
    int k0 = wv * 48;
    const float* wr = ga_ih + (size_t)j * FIN_A;
    const float* wz = ga_ih + (size_t)(H2 + j) * FIN_A;
    const float* wn = ga_ih + (size_t)(2 * H2 + j) * FIN_A;
    float pr = 0.0f, pz = 0.0f, pn = 0.0f;
    #pragma unroll 8
    for (int kk = 0; kk < 48; ++kk) {
        int k = k0 + kk;                             // xaT row
        int wc = k + (k >= 256 ? 512 : 0);           // weight col (sv lives at 768..895)
        float xv = xaT[k * 64 + lane];
        pr += wr[wc] * xv; pz += wz[wc] * xv; pn += wn[wc] * xv;
    }
    __shared__ float s[3][8][64];
    s[0][wv][lane] = pr; s[1][wv][lane] = pz; s[2][wv][lane] = pn;
    __syncthreads();
    if (wv == 0) {
        float fr = 0.0f, fz = 0.0f, fn = 0.0f;
        #pragma unroll
        for (int q = 0; q < 8; ++q) { fr += s[0][q][lane]; fz += s[1][q][lane]; fn += s[2][q][lane]; }
        float r = fast_sigmoid(fr + ga_bih[j] + ga_bhh[j]);
        float z = fast_sigmoid(fz + ga_bih[H2 + j] + ga_bhh[H2 + j]);
        float nn = fast_tanh(fn + ga_bih[2 * H2 + j] + r * ga_bhh[2 * H2 + j]);
        out_decT[(H2 + j) * 64 + lane] = (1.0f - z) * nn;
    }
}

// ---- Stage 4: attW_dec[n][i] = out_att @ wdec.T + bdec. Block per i; 8 waves split K=512.
__global__ __launch_bounds__(512) void k_attw(const float* __restrict__ out_decT,
                                              const float* __restrict__ wdec,
                                              const float* __restrict__ bdec,
                                              float* __restrict__ attW_dec) {
    int i = blockIdx.x;                              // 0..511
    int wv = threadIdx.x >> 6, lane = threadIdx.x & 63;
    int k0 = wv * 64;
    const float* w = wdec + (size_t)i * H2 + k0;
    const float* xT = out_decT + (H2 + k0) * 64;
    float p = 0.0f;
    #pragma unroll 8
    for (int k = 0; k < 64; ++k) p += w[k] * xT[k * 64 + lane];
    __shared__ float s[8][64];
    s[wv][lane] = p;
    __syncthreads();
    if (wv == 0) {
        float acc = 0.0f;
        #pragma unroll
        for (int q = 0; q < 8; ++q) acc += s[q][lane];
        attW_dec[lane * H2 + i] = acc + bdec[i];
    }
}

// ---- Stage 5: FUSED score+apply, length-balanced. Block (c,p) handles chunk c of
// BOTH n=p and n=63-p (lengths sorted desc -> pair work ~constant). Phase 1: 32
// scores -> LDS; phase 2: stream enc. Coalesced num_part [c][n][d].
__global__ __launch_bounds__(256) void k_attn(
        const float* __restrict__ enc, const float* __restrict__ attw_enc,
        const float* __restrict__ attW_dec, const float* __restrict__ wattn,
        const float* __restrict__ battn, const int* __restrict__ lengths,
        float* __restrict__ num_part /*[CH][NB][512]*/,
        float* __restrict__ den_part /*[CH][NB]*/) {
    int p = blockIdx.y;                              // 0..31
    int c = blockIdx.x;                              // 0..31
    int wv = threadIdx.x >> 6, lane = threadIdx.x & 63;
    int t0 = c * (TT / CH);
    __shared__ float sew[TT / CH];
    __shared__ float s[4 * 512];
    __shared__ float sd[4];
    const float4* w4 = (const float4*)wattn;
    float b = battn[0];

    #pragma unroll
    for (int half = 0; half < 2; ++half) {
        int n = half ? (63 - p) : p;
        int len = lengths[n];

        // phase 1: scores for rows t0+wv*8 .. +8
        {
            const float4* d4 = (const float4*)(attW_dec + n * H2);
            #pragma unroll
            for (int r = 0; r < 8; ++r) {
                int t = t0 + wv * 8 + r;
                float val = 0.0f;
                if (t < len) {                       // wave-uniform
                    const float4* e4 = (const float4*)(attw_enc + ((size_t)(n * TT + t)) * H2);
                    float pp = 0.0f;
                    #pragma unroll
                    for (int m = 0; m < 2; ++m) {
                        int idx = lane + m * 64;
                        float4 e = e4[idx], d = d4[idx], w = w4[idx];
                        pp += fast_tanh(e.x + d.x) * w.x + fast_tanh(e.y + d.y) * w.y +
                              fast_tanh(e.z + d.z) * w.z + fast_tanh(e.w + d.w) * w.w;
                    }
                    pp = wred(pp);
                    val = __expf(pp + b);
                }
                if (lane == 0) sew[wv * 8 + r] = val;
            }
        }
        __syncthreads();

        // phase 2: weighted accumulate over the same 8 rows per wave
        int d0 = lane * 8;
        const float* base = enc + ((size_t)(n * TT + t0 + wv * 8)) * H2 + d0;
        float4 a0 = {0, 0, 0, 0}, a1 = {0, 0, 0, 0};
        float dp = 0.0f;
        #pragma unroll
        for (int r = 0; r < 8; ++r) {
            float wt = sew[wv * 8 + r];
            if (wt != 0.0f) {                        // wave-uniform skip
                const float4* v4 = (const float4*)(base + (size_t)r * H2);
                float4 v0 = v4[0], v1 = v4[1];
                a0.x += wt * v0.x; a0.y += wt * v0.y; a0.z += wt * v0.z; a0.w += wt * v0.w;
                a1.x += wt * v1.x; a1.y += wt * v1.y; a1.z += wt * v1.z; a1.w += wt * v1.w;
                dp += wt;
            }
        }
        float4* srow = (float4*)(s + wv * 512 + d0);
        srow[0] = a0; srow[1] = a1;
        if (lane == 0) sd[wv] = dp;
        __syncthreads();
        int d = threadIdx.x;
        float r0 = s[d] + s[512 + d] + s[1024 + d] + s[1536 + d];
        float r1 = s[256 + d] + s[768 + d] + s[1280 + d] + s[1792 + d];
        float* np = num_part + ((size_t)(c * NB + n)) * H2;   // coalesced [c][n][d]
        np[d] = r0;
        np[256 + d] = r1;
        if (threadIdx.x == 0) den_part[c * NB + n] = sd[0] + sd[1] + sd[2] + sd[3];
        __syncthreads();                             // LDS reused by next half
    }
}

// ---- Stage 6: reduce partials; write attn_applied (output 1) + out_decT rows 0..511.
// Block (n, d-half); num_part reads coalesced; out_decT transpose scatter (2 MB eff).
__global__ void k_reduce(const float* __restrict__ num_part, const float* __restrict__ den_part,
                         float* __restrict__ out, float* __restrict__ out_decT) {
    int n = blockIdx.x;                              // 0..63
    int d = blockIdx.y * 256 + threadIdx.x;          // 0..511
    float s = 0.0f, den = 0.0f;
    #pragma unroll 8
    for (int c = 0; c < CH; ++c) {
        s += num_part[((size_t)(c * NB + n)) * H2 + d];
        den += den_part[c * NB + n];
    }
    float a = s / fmaxf(den, 1e-12f);
    out[NB * 160 + n * H2 + d] = a;                  // output 1: attn_applied (n-major)
    out_decT[(size_t)d * 64 + n] = a;                // transposed for the GEMM chain
}

// ---- Stage 7: res1T = (out_dec @ wsc.T + bsc + GRU1(out_dec,0))^T. Block per j; 8 waves split K=1152.
__global__ __launch_bounds__(512) void k_sc_h1(const float* __restrict__ out_decT,
                                               const float* __restrict__ wsc,
                                               const float* __restrict__ bsc,
                                               const float* __restrict__ g1_ih,
                                               const float* __restrict__ g1_bih,
                                               const float* __restrict__ g1_bhh,
                                               float* __restrict__ res1T) {
    int j = blockIdx.x;                              // 0..511
    int wv = threadIdx.x >> 6, lane = threadIdx.x & 63;
    int k0 = wv * 144;
    const float* ws_ = wsc + (size_t)j * FIN_1 + k0;
    const float* wr = g1_ih + (size_t)j * FIN_1 + k0;
    const float* wz = g1_ih + (size_t)(H2 + j) * FIN_1 + k0;
    const float* wn = g1_ih + (size_t)(2 * H2 + j) * FIN_1 + k0;
    const float* xT = out_decT + k0 * 64;
    float2 ps = {0, 0}, pr = {0, 0}, pz = {0, 0}, pn = {0, 0};
    #pragma unroll 4
    for (int k = 0; k < 144; k += 2) {
        float x0 = xT[k * 64 + lane];
        float x1 = xT[(k + 1) * 64 + lane];
        float2 a = *(const float2*)(ws_ + k);
        float2 bb = *(const float2*)(wr + k);
        float2 cc = *(const float2*)(wz + k);
        float2 dd = *(const float2*)(wn + k);
        ps.x += a.x * x0; ps.y += a.y * x1;
        pr.x += bb.x * x0; pr.y += bb.y * x1;
        pz.x += cc.x * x0; pz.y += cc.y * x1;
        pn.x += dd.x * x0; pn.y += dd.y * x1;
    }
    __shared__ float s[4][8][64];
    s[0][wv][lane] = ps.x + ps.y; s[1][wv][lane] = pr.x + pr.y;
    s[2][wv][lane] = pz.x + pz.y; s[3][wv][lane] = pn.x + pn.y;
    __syncthreads();
    if (wv == 0) {
        float fs = 0.0f, fr = 0.0f, fz = 0.0f, fn = 0.0f;
        #pragma unroll
        for (int q = 0; q < 8; ++q) {
            fs += s[0][q][lane]; fr += s[1][q][lane];
            fz += s[2][q][lane]; fn += s[3][q][lane];
        }
        float r = fast_sigmoid(fr + g1_bih[j] + g1_bhh[j]);
        float z = fast_sigmoid(fz + g1_bih[H2 + j] + g1_bhh[H2 + j]);
        float nn = fast_tanh(fn + g1_bih[2 * H2 + j] + r * g1_bhh[2 * H2 + j]);
        res1T[j * 64 + lane] = fs + bsc[j] + (1.0f - z) * nn;
    }
}

// ---- Stage 8: res2T = res1T + GRU2(res1,0)^T. Block per j; 8 waves split K=512.
__global__ __launch_bounds__(512) void k_h2(const float* __restrict__ res1T,
                                            const float* __restrict__ g2_ih,
                                            const float* __restrict__ g2_bih,
                                            const float* __restrict__ g2_bhh,
                                            float* __restrict__ res2T) {
    int j = blockIdx.x;                              // 0..511
    int wv = threadIdx.x >> 6, lane = threadIdx.x & 63;
    int k0 = wv * 64;
    const float* wr = g2_ih + (size_t)j * H2 + k0;
    const float* wz = g2_ih + (size_t)(H2 + j) * H2 + k0;
    const float* wn = g2_ih + (size_t)(2 * H2 + j) * H2 + k0;
    const float* xT = res1T + k0 * 64;
    float pr = 0.0f, pz = 0.0f, pn = 0.0f;
    #pragma unroll 8
    for (int k = 0; k < 64; ++k) {
        float xv = xT[k * 64 + lane];
        pr += wr[k] * xv; pz += wz[k] * xv; pn += wn[k] * xv;
    }
    __shared__ float s[3][8][64];
    s[0][wv][lane] = pr; s[1][wv][lane] = pz; s[2][wv][lane] = pn;
    __syncthreads();
    if (wv == 0) {
        float fr = 0.0f, fz = 0.0f, fn = 0.0f;
        #pragma unroll
        for (int q = 0; q < 8; ++q) { fr += s[0][q][lane]; fz += s[1][q][lane]; fn += s[2][q][lane]; }
        float r = fast_sigmoid(fr + g2_bih[j] + g2_bhh[j]);
        float z = fast_sigmoid(fz + g2_bih[H2 + j] + g2_bhh[H2 + j]);
        float nn = fast_tanh(fn + g2_bih[2 * H2 + j] + r * g2_bhh[2 * H2 + j]);
        res2T[j * 64 + lane] = res1T[j * 64 + lane] + (1.0f - z) * nn;
    }
}

// ---- Stage 9: out[0..10240) = res2 @ wout.T + bout. Block per i; 8 waves split K=512.
__global__ __launch_bounds__(512) void k_out(const float* __restrict__ res2T,
                                             const float* __restrict__ wout,
                                             const float* __restrict__ bout,
                                             float* __restrict__ out) {
    int i = blockIdx.x;                              // 0..159
    int wv = threadIdx.x >> 6, lane = threadIdx.x & 63;
    int k0 = wv * 64;
    const float* w = wout + (size_t)i * H2 + k0;
    const float* xT = res2T + k0 * 64;
    float p = 0.0f;
    #pragma unroll 8
    for (int k = 0; k < 64; ++k) p += w[k] * xT[k * 64 + lane];
    __shared__ float s[8][64];
    s[wv][lane] = p;
    __syncthreads();
    if (wv == 0) {
        float acc = 0.0f;
        #pragma unroll
        for (int q = 0; q < 8; ++q) acc += s[q][lane];
        out[lane * 160 + i] = acc + bout[i];
    }
}

extern "C" void kernel_launch(void* const* d_in, const int* in_sizes, int n_in,
                              void* d_out, int out_size, void* d_ws, size_t ws_size,
                              hipStream_t stream) {
    const float* input_enc      = (const float*)d_in[0];
    const float* input_attW_enc = (const float*)d_in[1];
    const float* input_dec      = (const float*)d_in[2];
    const float* style_vec      = (const float*)d_in[3];
    const int*   lengths_enc    = (const int*)d_in[4];
    const float* pw1  = (const float*)d_in[5];
    const float* pb1  = (const float*)d_in[6];
    const float* pw2  = (const float*)d_in[7];
    const float* pb2  = (const float*)d_in[8];
    const float* wdec = (const float*)d_in[9];
    const float* bdec = (const float*)d_in[10];
    const float* ga_ih  = (const float*)d_in[11];
    const float* ga_bih = (const float*)d_in[13];
    const float* ga_bhh = (const float*)d_in[14];
    const float* wattn  = (const float*)d_in[15];
    const float* battn  = (const float*)d_in[16];
    const float* wsc    = (const float*)d_in[17];
    const float* bsc    = (const float*)d_in[18];
    const float* g1_ih  = (const float*)d_in[19];
    const float* g1_bih = (const float*)d_in[21];
    const float* g1_bhh = (const float*)d_in[22];
    const float* g2_ih  = (const float*)d_in[23];
    const float* g2_bih = (const float*)d_in[25];
    const float* g2_bhh = (const float*)d_in[26];
    const float* wout   = (const float*)d_in[27];
    const float* bout   = (const float*)d_in[28];
    float* out = (float*)d_out;

    // workspace (floats); everything fully written before read — no zeroing needed
    float* ws = (float*)d_ws;
    float* num_part = ws;                         // CH*64*512 = 1048576
    float* den_part = ws + 1048576;               // CH*64    = 2048
    float* t1T      = ws + 1050624;               // 512*64   = 32768
    float* xaT      = ws + 1083392;               // 384*64   = 24576
    float* out_decT = ws + 1107968;               // 1152*64  = 73728
    float* attW_dec = ws + 1181696;               // 64*512   = 32768
    float* res1T    = ws + 1214464;               // 512*64   = 32768
    float* res2T    = ws + 1247232;               // 512*64   = 32768

    k_l1<<<160, 256, 0, stream>>>(input_dec, pw1, pb1, style_vec, t1T, xaT, out_decT);
    k_l2<<<256, 512, 0, stream>>>(t1T, pw2, pb2, xaT);
    k_gruA<<<512, 512, 0, stream>>>(xaT, ga_ih, ga_bih, ga_bhh, out_decT);
    k_attw<<<512, 512, 0, stream>>>(out_decT, wdec, bdec, attW_dec);
    k_attn<<<dim3(CH, 32), 256, 0, stream>>>(input_enc, input_attW_enc, attW_dec,
                                             wattn, battn, lengths_enc, num_part, den_part);
    k_reduce<<<dim3(64, 2), 256, 0, stream>>>(num_part, den_part, out, out_decT);
    k_sc_h1<<<512, 512, 0, stream>>>(out_decT, wsc, bsc, g1_ih, g1_bih, g1_bhh, res1T);
    k_h2<<<512, 512, 0, stream>>>(res1T, g2_ih, g2_bih, g2_bhh, res2T);
    k_out<<<160, 512, 0, stream>>>(res2T, wout, bout, out);
}